// Round 9
// baseline (121.717 us; speedup 1.0000x reference)
//
#include <hip/hip_runtime.h>
#include <stdint.h>

#define N_PTS 256

typedef unsigned long long ull;
typedef float v2f __attribute__((ext_vector_type(2)));

__device__ __forceinline__ unsigned umin2(unsigned a, unsigned b) { return a < b ? a : b; }

// Single-instruction DPP max stage (old=0 + bound_ctrl=1 = unsigned-max
// identity -> GCNDPPCombine folds to one v_max_u32_dpp; verified R7).
template<int CTRL>
__device__ __forceinline__ unsigned dppmax(unsigned x) {
    unsigned y = (unsigned)__builtin_amdgcn_update_dpp(0, (int)x, CTRL, 0xf, 0xf, true);
    return x > y ? x : y;
}

// Wave MIN of non-negative fp32 via complemented unsigned MAX (bit-exact;
// NaN complements below all live values). Single-chain version (redo path).
__device__ __forceinline__ unsigned wave_cmax1(float m) {
    unsigned c = ~__float_as_uint(m);
    c = dppmax<0x121>(c); c = dppmax<0x122>(c); c = dppmax<0x124>(c);
    c = dppmax<0x128>(c); c = dppmax<0x142>(c); c = dppmax<0x143>(c);
    return ~((unsigned)__builtin_amdgcn_readlane((int)c, 63));
}

// TWO independent chains interleaved: each fused v_max_u32_dpp has ~2 cycles
// of dependent-operand hazard; the other chain's stage fills that slot
// (the per-res issue-slot budget, incl. s_nops, is the measured limiter).
__device__ __forceinline__ void wave_cmax2(float mA, float mB,
                                           unsigned& muA, unsigned& muB) {
    unsigned a = ~__float_as_uint(mA);
    unsigned b = ~__float_as_uint(mB);
    a = dppmax<0x121>(a); b = dppmax<0x121>(b);
    a = dppmax<0x122>(a); b = dppmax<0x122>(b);
    a = dppmax<0x124>(a); b = dppmax<0x124>(b);
    a = dppmax<0x128>(a); b = dppmax<0x128>(b);
    a = dppmax<0x142>(a); b = dppmax<0x142>(b);
    a = dppmax<0x143>(a); b = dppmax<0x143>(b);
    muA = ~((unsigned)__builtin_amdgcn_readlane((int)a, 63));
    muB = ~((unsigned)__builtin_amdgcn_readlane((int)b, 63));
}

// exact first-min-wins argmin: slot-major ballots + flat SALU tree
__device__ __forceinline__ unsigned argmin_ballots(
    float d0, float d1, float d2, float d3, float ms) {
    ull e0 = __ballot(d0 == ms);
    ull e1 = __ballot(d1 == ms);
    ull e2 = __ballot(d2 == ms);
    ull e3 = __ballot(d3 == ms);
    unsigned u0 = (unsigned)(__ffsll((long long)e0) - 1);
    unsigned u1 = ((unsigned)(__ffsll((long long)e1) - 1)) | 64u;
    unsigned u2 = ((unsigned)(__ffsll((long long)e2) - 1)) | 128u;
    unsigned u3 = ((unsigned)(__ffsll((long long)e3) - 1)) | 192u;
    return umin2(umin2(u0, u1), umin2(u2, u3));
}

__device__ __forceinline__ void poison(unsigned k, unsigned lane, float vNAN,
                                       v2f& p0, v2f& p1, v2f& p2, v2f& p3) {
    unsigned ks = k >> 6, kl = k & 63u;
    bool hit = (lane == kl);
    p0.x = (hit && ks == 0) ? vNAN : p0.x;
    p1.x = (hit && ks == 1) ? vNAN : p1.x;
    p2.x = (hit && ks == 2) ? vNAN : p2.x;
    p3.x = (hit && ks == 3) ? vNAN : p3.x;
}

#define DIST4(tx, ty, D0, D1, D2, D3)                                  \
    {                                                                  \
        v2f t; t.x = (tx); t.y = (ty);                                 \
        v2f q0 = t - p0, q1 = t - p1, q2 = t - p2, q3 = t - p3;        \
        v2f s0 = q0 * q0, s1 = q1 * q1, s2 = q2 * q2, s3 = q3 * q3;    \
        D0 = s0.x + s0.y; D1 = s1.x + s1.y;                            \
        D2 = s2.x + s2.y; D3 = s3.x + s3.y;                            \
    }

// One 64-target phase as 32 speculative PAIRS (j, j+1), both over the pre-A
// set. A exact; B valid unless argminB == kA (removing a non-winner never
// changes a min); rare collision -> wave-uniform redo. Validated absmax 0.0
// in R3. Pairing now pays off because the fused DPP chains interleave.
__device__ __forceinline__ void phase(
    float txc, float tyc, unsigned lane, float& acc,
    v2f& p0, v2f& p1, v2f& p2, v2f& p3, float vNAN)
{
    #pragma clang fp contract(off)
    const unsigned BIG_U = __float_as_uint(66049.0f); // 257^2
    #pragma unroll 1
    for (int j = 0; j < 64; j += 2) {
        float tAx = __int_as_float(__builtin_amdgcn_readlane(__float_as_int(txc), j));
        float tAy = __int_as_float(__builtin_amdgcn_readlane(__float_as_int(tyc), j));
        float tBx = __int_as_float(__builtin_amdgcn_readlane(__float_as_int(txc), j + 1));
        float tBy = __int_as_float(__builtin_amdgcn_readlane(__float_as_int(tyc), j + 1));

        float dA0, dA1, dA2, dA3, dB0, dB1, dB2, dB3;
        DIST4(tAx, tAy, dA0, dA1, dA2, dA3);
        DIST4(tBx, tBy, dB0, dB1, dB2, dB3);

        float mA = fminf(fminf(dA0, dA1), fminf(dA2, dA3));
        float mB = fminf(fminf(dB0, dB1), fminf(dB2, dB3));
        unsigned muA, muB;
        wave_cmax2(mA, mB, muA, muB);
        float msA = __uint_as_float(muA);
        float msB = __uint_as_float(muB);

        unsigned kA = argmin_ballots(dA0, dA1, dA2, dA3, msA);
        unsigned kB = argmin_ballots(dB0, dB1, dB2, dB3, msB);

        // resolve A exactly
        bool okA = (muA < BIG_U);
        kA = okA ? kA : 0u;
        acc += __uint_as_float(umin2(muA, BIG_U));
        poison(kA, lane, vNAN, p0, p1, p2, p3);

        // resolve B; redo iff its pick was just consumed by A (uniform branch)
        if (kB == kA) {
            float r0, r1, r2, r3;
            DIST4(tBx, tBy, r0, r1, r2, r3);
            float m2 = fminf(fminf(r0, r1), fminf(r2, r3));
            muB = wave_cmax1(m2);
            msB = __uint_as_float(muB);
            kB = argmin_ballots(r0, r1, r2, r3, msB);
        }
        bool okB = (muB < BIG_U);
        kB = okB ? kB : 0u;
        acc += __uint_as_float(umin2(muB, BIG_U));
        poison(kB, lane, vNAN, p0, p1, p2, p3);
    }
}

// One wave per batch, 2 waves/SIMD (B=2048-capped; R5 proved 1/SIMD is 2x worse).
__global__ __launch_bounds__(256) void greedy_match_kernel(
    const float* __restrict__ input,
    const float* __restrict__ targets,
    float* __restrict__ out,
    int B, float scale)
{
    __shared__ float wsum[4];
    const unsigned lane = threadIdx.x & 63;
    const int wid  = threadIdx.x >> 6;
    const int b    = blockIdx.x * 4 + wid;

    float acc = 0.0f;
    if (b < B) {
        const v2f* pin = (const v2f*)(input   + (size_t)b * (2 * N_PTS));
        const v2f* ptg = (const v2f*)(targets + (size_t)b * (2 * N_PTS));

        v2f p0 = pin[lane],       p1 = pin[64 + lane];
        v2f p2 = pin[128 + lane], p3 = pin[192 + lane];
        v2f t0 = ptg[lane],       t1 = ptg[64 + lane];
        v2f t2 = ptg[128 + lane], t3 = ptg[192 + lane];

        const float vNAN = __int_as_float(0x7fc00000);

        phase(t0.x, t0.y, lane, acc, p0, p1, p2, p3, vNAN);
        phase(t1.x, t1.y, lane, acc, p0, p1, p2, p3, vNAN);
        phase(t2.x, t2.y, lane, acc, p0, p1, p2, p3, vNAN);
        phase(t3.x, t3.y, lane, acc, p0, p1, p2, p3, vNAN);
    }

    if (lane == 0) wsum[wid] = acc;
    __syncthreads();
    if (threadIdx.x == 0) {
        float s = (wsum[0] + wsum[1] + wsum[2] + wsum[3]) * scale;
        atomicAdd(out, s);
    }
}

extern "C" void kernel_launch(void* const* d_in, const int* in_sizes, int n_in,
                              void* d_out, int out_size, void* d_ws, size_t ws_size,
                              hipStream_t stream) {
    const float* input   = (const float*)d_in[0];
    const float* targets = (const float*)d_in[1];
    float* out = (float*)d_out;

    const int B = in_sizes[0] / (2 * N_PTS);
    const float scale = 1.0f / ((float)B * (float)(2 * N_PTS));

    // d_out is poisoned 0xAA before every call — zero it (graph-capturable).
    hipMemsetAsync(d_out, 0, sizeof(float) * (size_t)out_size, stream);

    const int blocks = (B + 3) / 4;  // 4 waves (4 batches) per 256-thread block
    greedy_match_kernel<<<blocks, 256, 0, stream>>>(input, targets, out, B, scale);
}